// Round 5
// baseline (185.616 us; speedup 1.0000x reference)
//
#include <hip/hip_runtime.h>

#define F_EPS 1e-12f
#define F_DAMPING 0.95f
#define N_ITER 6
#define TPB 256
#define TILES 4   // thread-tiles per thread; 16 rays/thread total

// Streaming kernel, zero barriers. Each thread owns TILES tiles of 4 rays.
// Register double-buffer: tile j+1's 6 float4 loads are issued BEFORE tile j's
// compute, so every wave keeps ~6KB of loads in flight through its compute
// phase (intra-wave latency hiding; TLP alone was insufficient — R2/R3/R4 all
// pinned at ~58-60us with both pipes <31% busy).
__launch_bounds__(TPB)
__global__ void trace_kernel(const float* __restrict__ P,
                             const float* __restrict__ V,
                             const float* __restrict__ tf,
                             const float* __restrict__ diameter,
                             const float* __restrict__ Cc,
                             const float* __restrict__ anchors,
                             const float* __restrict__ scale_p,
                             const unsigned char* __restrict__ normalize,
                             float* __restrict__ out,
                             int n)
{
    const int tid = threadIdx.x;

    // ---- uniform params (precise, contraction off; reference op order) ----
    float R0,R1,R2,R3,R4,R5,R6,R7,R8, tv0,tv1,tv2;
    float C_eff, scale, half_d2, inv_s2;
    {
#pragma clang fp contract(off)
        float d  = diameter[0];
        float c  = Cc[0];
        float sc = scale_p[0];
        bool  nrm = (normalize[0] != 0);
        C_eff = nrm ? (c * 2.0f / d) : c;
        float s2 = sc * sc;
        float hr = d * 0.5f;
        half_d2 = hr * hr;
        float u = half_d2 / s2;
        float root = sqrtf(fmaxf(1.0f - (C_eff * C_eff) * u, F_EPS));
        float extent = sc * C_eff * u / (1.0f + root);
        float a0 = anchors[0], a1 = anchors[1];
        float dx0 = -a0 * extent;
        float dx1 = (a1 - a0) * extent;
        R0 = tf[0]; R1 = tf[1]; R2 = tf[2];
        R3 = tf[4]; R4 = tf[5]; R5 = tf[6];
        R6 = tf[8]; R7 = tf[9]; R8 = tf[10];
        tv0 = tf[0] * dx0 + tf[3];
        tv1 = tf[4] * dx0 + tf[7];
        tv2 = tf[8] * dx0 + tf[11];
        scale  = sc;
        inv_s2 = 1.0f / s2;
        if (blockIdx.x == 0 && tid < 16) {
            int i = tid >> 2, j = tid & 3;
            float v  = tf[tid];
            float sv = (j == 3) ? (tf[i * 4] * dx0 + v) : v;
            float nv = (j == 3) ? (tf[i * 4] * dx1 + v) : v;
            float* out_tail = out + (size_t)n * 5;
            out_tail[tid]      = sv;
            out_tail[16 + tid] = nv;
        }
    }
    const float ce2   = C_eff * C_eff;
    const float sC    = scale * C_eff;
    const float a_num = sC * inv_s2;          // F = a_num*r2/(1+root) - p.x
    const float ce2s  = ce2 * inv_s2;         // m = 1 - ce2s*r2
    const float Cs    = C_eff / scale;        // k = Cs * rsq(m)

    const float4* P4 = reinterpret_cast<const float4*>(P);
    const float4* V4 = reinterpret_cast<const float4*>(V);
    float* t_out = out;
    float* n_out = out + (size_t)n;
    float* v_out = out + (size_t)n * 4;

    // thread-tile linear index for tile j: u = (blockIdx.x*TILES + j)*TPB + tid
    // rays [4u, 4u+4); float4 base index 3u (AoS xyz, 48B lane stride).

    float4 c0,c1,c2,c3,c4,c5;   // current tile regs (P:0-2, V:3-5)
    float4 x0,x1,x2,x3,x4,x5;   // next tile regs

    // prologue: load tile 0
    {
        size_t u = ((size_t)blockIdx.x * TILES + 0) * TPB + tid;
        long base = (long)u * 4;
        if (base + 4 <= n) {
            c0 = P4[u*3+0]; c1 = P4[u*3+1]; c2 = P4[u*3+2];
            c3 = V4[u*3+0]; c4 = V4[u*3+1]; c5 = V4[u*3+2];
        } else {
            float tmp[12];
            for (int r = 0; r < 4; ++r) {
                long i = base + r;
                if (i < n) {
                    tmp[r*3+0] = P[i*3+0]; tmp[r*3+1] = P[i*3+1]; tmp[r*3+2] = P[i*3+2];
                } else { tmp[r*3+0] = 0.0f; tmp[r*3+1] = 0.0f; tmp[r*3+2] = 0.0f; }
            }
            c0 = make_float4(tmp[0],tmp[1],tmp[2],tmp[3]);
            c1 = make_float4(tmp[4],tmp[5],tmp[6],tmp[7]);
            c2 = make_float4(tmp[8],tmp[9],tmp[10],tmp[11]);
            for (int r = 0; r < 4; ++r) {
                long i = base + r;
                if (i < n) {
                    tmp[r*3+0] = V[i*3+0]; tmp[r*3+1] = V[i*3+1]; tmp[r*3+2] = V[i*3+2];
                } else { tmp[r*3+0] = 1.0f; tmp[r*3+1] = 0.0f; tmp[r*3+2] = 0.0f; }
            }
            c3 = make_float4(tmp[0],tmp[1],tmp[2],tmp[3]);
            c4 = make_float4(tmp[4],tmp[5],tmp[6],tmp[7]);
            c5 = make_float4(tmp[8],tmp[9],tmp[10],tmp[11]);
        }
    }

#pragma unroll
    for (int j = 0; j < TILES; ++j) {
        // ---- issue prefetch for tile j+1 (overlaps compute below) ----
        if (j + 1 < TILES) {
            size_t u1 = ((size_t)blockIdx.x * TILES + (j+1)) * TPB + tid;
            long base1 = (long)u1 * 4;
            if (base1 + 4 <= n) {
                x0 = P4[u1*3+0]; x1 = P4[u1*3+1]; x2 = P4[u1*3+2];
                x3 = V4[u1*3+0]; x4 = V4[u1*3+1]; x5 = V4[u1*3+2];
            } else {
                x0 = make_float4(0,0,0,0); x1 = x0; x2 = x0;
                x3 = make_float4(1,0,0,1); x4 = make_float4(0,0,1,0); x5 = make_float4(0,0,1,0);
                for (int r = 0; r < 4; ++r) {
                    long i = base1 + r;
                    if (i < n) {
                        float px = P[i*3+0], py = P[i*3+1], pz = P[i*3+2];
                        float qx = V[i*3+0], qy = V[i*3+1], qz = V[i*3+2];
                        if (r==0) { x0.x=px; x0.y=py; x0.z=pz; x3.x=qx; x3.y=qy; x3.z=qz; }
                        if (r==1) { x0.w=px; x1.x=py; x1.y=pz; x3.w=qx; x4.x=qy; x4.y=qz; }
                        if (r==2) { x1.z=px; x1.w=py; x2.x=pz; x4.z=qx; x4.w=qy; x5.x=qz; }
                        if (r==3) { x2.y=px; x2.z=py; x2.w=pz; x5.y=qx; x5.z=qy; x5.w=qz; }
                    }
                }
            }
        }

        // ---- compute tile j from current regs ----
        size_t u = ((size_t)blockIdx.x * TILES + j) * TPB + tid;
        long base = (long)u * 4;
        if (base < n) {
            float Px[4], Py[4], Pz[4], Vx[4], Vy[4], Vz[4];
            Px[0]=c0.x; Py[0]=c0.y; Pz[0]=c0.z; Px[1]=c0.w; Py[1]=c1.x; Pz[1]=c1.y;
            Px[2]=c1.z; Py[2]=c1.w; Pz[2]=c2.x; Px[3]=c2.y; Py[3]=c2.z; Pz[3]=c2.w;
            Vx[0]=c3.x; Vy[0]=c3.y; Vz[0]=c3.z; Vx[1]=c3.w; Vy[1]=c4.x; Vz[1]=c4.y;
            Vx[2]=c4.z; Vy[2]=c4.w; Vz[2]=c5.x; Vx[3]=c5.y; Vy[3]=c5.z; Vz[3]=c5.w;
            // guard padded rays in a partial tile
            if (base + 4 > n) {
                for (int r = 0; r < 4; ++r)
                    if (base + r >= n) { Px[r]=0; Py[r]=0; Pz[r]=0; Vx[r]=1; Vy[r]=0; Vz[r]=0; }
            }

            float Plx[4], Ply[4], Plz[4], vx[4], vy[4], vz[4], tN[4];
#pragma unroll
            for (int r = 0; r < 4; ++r) {
                float px0 = Px[r] - tv0, py0 = Py[r] - tv1, pz0 = Pz[r] - tv2;
                Plx[r] = px0 * R0 + py0 * R3 + pz0 * R6;
                Ply[r] = px0 * R1 + py0 * R4 + pz0 * R7;
                Plz[r] = px0 * R2 + py0 * R5 + pz0 * R8;
                vx[r] = Vx[r] * R0 + Vy[r] * R3 + Vz[r] * R6;
                vy[r] = Vx[r] * R1 + Vy[r] * R4 + Vz[r] * R7;
                vz[r] = Vx[r] * R2 + Vy[r] * R5 + Vz[r] * R8;
                float safe_vx = (fabsf(vx[r]) > F_EPS) ? vx[r] : F_EPS;
                tN[r] = (-Plx[r]) * __builtin_amdgcn_rcpf(safe_vx);
            }
#pragma unroll
            for (int it = 0; it < N_ITER; ++it) {
#pragma unroll
                for (int r = 0; r < 4; ++r) {
                    float pxx = fmaf(tN[r], vx[r], Plx[r]);
                    float py  = fmaf(tN[r], vy[r], Ply[r]);
                    float pz  = fmaf(tN[r], vz[r], Plz[r]);
                    float r2  = fmaf(py, py, pz * pz);
                    float m   = fmaxf(fmaf(-ce2s, r2, 1.0f), F_EPS);
                    float rsq = __builtin_amdgcn_rsqf(m);
                    float root = m * rsq;
                    float k    = Cs * rsq;
                    float ird  = __builtin_amdgcn_rcpf(1.0f + root);
                    float F    = fmaf(a_num * r2, ird, -pxx);
                    float dF = fmaf(k * py, vy[r], fmaf(k * pz, vz[r], -vx[r]));
                    dF = (fabsf(dF) > F_EPS) ? dF : F_EPS;
                    tN[r] = fmaf(-F_DAMPING * F, __builtin_amdgcn_rcpf(dF), tN[r]);
                }
            }
            float tres[4], nxo[4], nyo[4], nzo[4], val[4];
#pragma unroll
            for (int r = 0; r < 4; ++r) {
                float pxx = fmaf(tN[r], vx[r], Plx[r]);
                float py  = fmaf(tN[r], vy[r], Ply[r]);
                float pz  = fmaf(tN[r], vz[r], Plz[r]);
                float r2  = fmaf(py, py, pz * pz);
                float m   = fmaxf(fmaf(-ce2s, r2, 1.0f), F_EPS);
                float rsq = __builtin_amdgcn_rsqf(m);
                float root = m * rsq;
                float k    = Cs * rsq;
                float ird  = __builtin_amdgcn_rcpf(1.0f + root);
                float F    = fmaf(a_num * r2, ird, -pxx);
                float gy = k * py, gz = k * pz;
                float nn2 = fmaf(gy, gy, fmaf(gz, gz, 1.0f));
                float irn = __builtin_amdgcn_rsqf(nn2);
                float nlx = -irn, nly = gy * irn, nlz = gz * irn;
                nxo[r] = nlx * R0 + nly * R1 + nlz * R2;
                nyo[r] = nlx * R3 + nly * R4 + nlz * R5;
                nzo[r] = nlx * R6 + nly * R7 + nlz * R8;
                tres[r] = tN[r];
                val[r]  = ((r2 <= half_d2) && (fabsf(F) < 1e-4f)) ? 1.0f : 0.0f;
            }

            if (base + 4 <= n) {
                reinterpret_cast<float4*>(t_out)[u] = make_float4(tres[0], tres[1], tres[2], tres[3]);
                float4* N4 = reinterpret_cast<float4*>(n_out);
                N4[u*3+0] = make_float4(nxo[0], nyo[0], nzo[0], nxo[1]);
                N4[u*3+1] = make_float4(nyo[1], nzo[1], nxo[2], nyo[2]);
                N4[u*3+2] = make_float4(nzo[2], nxo[3], nyo[3], nzo[3]);
                reinterpret_cast<float4*>(v_out)[u] = make_float4(val[0], val[1], val[2], val[3]);
            } else {
                for (int r = 0; r < 4; ++r) {
                    long i = base + r;
                    if (i < n) {
                        t_out[i] = tres[r];
                        n_out[i*3+0] = nxo[r];
                        n_out[i*3+1] = nyo[r];
                        n_out[i*3+2] = nzo[r];
                        v_out[i] = val[r];
                    }
                }
            }
        }

        // rotate buffers
        c0 = x0; c1 = x1; c2 = x2; c3 = x3; c4 = x4; c5 = x5;
    }
}

extern "C" void kernel_launch(void* const* d_in, const int* in_sizes, int n_in,
                              void* d_out, int out_size, void* d_ws, size_t ws_size,
                              hipStream_t stream) {
    const float* P  = (const float*)d_in[0];
    const float* V  = (const float*)d_in[1];
    const float* tf = (const float*)d_in[2];
    const float* diameter = (const float*)d_in[3];
    const float* C  = (const float*)d_in[4];
    const float* anchors = (const float*)d_in[5];
    const float* scale = (const float*)d_in[6];
    const unsigned char* normalize = (const unsigned char*)d_in[7];
    int n = in_sizes[0] / 3;
    float* out = (float*)d_out;

    long rays_per_block = (long)TPB * 4 * TILES;
    int blocks = (int)((n + rays_per_block - 1) / rays_per_block);
    trace_kernel<<<blocks, TPB, 0, stream>>>(P, V, tf, diameter, C, anchors, scale,
                                             normalize, out, n);
}